// Round 1
// baseline (3778.053 us; speedup 1.0000x reference)
//
#include <hip/hip_runtime.h>
#include <hip/hip_bf16.h>
#include <math.h>

// Problem constants
#define TSTEPS 40
#define GATED  30
#define BATCH  4096
#define XD     150
#define HD     150
#define G4     600      // 4*HD
#define KPAD   304      // 150 (x) + 150 (h) + 4 zero pad, float4-friendly
#define ROWS   16       // batch rows per block
#define NTHREADS 512    // 8 waves

// Output packing (flat fp32):
//   outh:    [4096,150]      offset 0
//   outputs: [40,4096,150]   offset 614400
//   ys:      [30,4096,2]     offset 25190400
#define OFF_OUTPUTS 614400
#define OFF_YS      25190400

__device__ __forceinline__ float sigf(float x) {
    return 1.0f / (1.0f + __expf(-x));
}
__device__ __forceinline__ float tanh_fast(float x) {
    x = fminf(fmaxf(x, -15.0f), 15.0f);
    float t = __expf(2.0f * x);
    return (t - 1.0f) / (t + 1.0f);
}

// Pack combined weights into workspace:
//   Wc [600][304]: cols 0..149 = w_ih[j][k], 150..299 = w_hh[j][k-150], 300..303 = 0
//   w1c [50][304]: LDS tile is [x | h], but stop-gate input is concat(h, x):
//                  cols 0..149 (x part)  = w1[j][150+k]
//                  cols 150..299 (h part)= w1[j][k-150]
//   bc [600] = b_ih + b_hh
__global__ void pack_weights(const float* __restrict__ w_ih, const float* __restrict__ w_hh,
                             const float* __restrict__ b_ih, const float* __restrict__ b_hh,
                             const float* __restrict__ w1,
                             float* __restrict__ Wc, float* __restrict__ w1c,
                             float* __restrict__ bc) {
    int idx = blockIdx.x * blockDim.x + threadIdx.x;
    int stride = gridDim.x * blockDim.x;
    for (int i = idx; i < G4 * KPAD; i += stride) {
        int j = i / KPAD, k = i % KPAD;
        float v = 0.0f;
        if (k < 150)      v = w_ih[j * 150 + k];
        else if (k < 300) v = w_hh[j * 150 + (k - 150)];
        Wc[i] = v;
    }
    for (int i = idx; i < 50 * KPAD; i += stride) {
        int j = i / KPAD, k = i % KPAD;
        float v = 0.0f;
        if (k < 150)      v = w1[j * 300 + 150 + k];   // x part
        else if (k < 300) v = w1[j * 300 + (k - 150)]; // h part
        w1c[i] = v;
    }
    for (int i = idx; i < G4; i += stride) bc[i] = b_ih[i] + b_hh[i];
}

__global__ __launch_bounds__(NTHREADS)
void lstm_main(const float* __restrict__ x,
               const float* __restrict__ Wc, const float* __restrict__ bc,
               const float* __restrict__ w1c, const float* __restrict__ b1,
               const float* __restrict__ w2, const float* __restrict__ b2,
               const float* __restrict__ w3, const float* __restrict__ b3,
               float* __restrict__ outh, float* __restrict__ outputs,
               float* __restrict__ ys) {
    __shared__ float sxh[ROWS][KPAD];   // [x(0..149) | h(150..299) | pad]
    __shared__ float sg[ROWS][G4];      // gate pre-activations
    __shared__ float st1[ROWS][50];
    __shared__ float st2[ROWS][25];

    const int tid = threadIdx.x;
    const int r  = tid & 15;    // row within block for compute phases
    const int jj = tid >> 4;    // 0..31: output-column group
    const int row0 = blockIdx.x * ROWS;

    // init h = 0 and zero pads (pads never rewritten; h rewritten each step)
    for (int i = tid; i < ROWS * KPAD; i += NTHREADS) {
        int rr = i / KPAD, k = i % KPAD;
        if (k >= 150) sxh[rr][k] = 0.0f;
    }
    // cell state in registers: k = jj + 32*m (at most 5 per thread)
    float creg[5];
#pragma unroll
    for (int m = 0; m < 5; ++m) creg[m] = 0.0f;

    __syncthreads();

    for (int t = 0; t < TSTEPS; ++t) {
        // ---- stage x_t tile into LDS (coalesced float2) ----
        const float* xt = x + ((size_t)t * BATCH + row0) * XD;
        for (int i = tid; i < ROWS * 75; i += NTHREADS) {
            int rr = i / 75, kk = i % 75;
            float2 v = *(const float2*)(xt + rr * XD + 2 * kk);
            *(float2*)&sxh[rr][2 * kk] = v;
        }
        __syncthreads();

        // ---- gate GEMV: sg[r][j] = bc[j] + [x|h] . Wc[j] ----
        for (int j = jj; j < G4; j += 32) {
            const float4* w4  = (const float4*)(Wc + (size_t)j * KPAD);
            const float4* xh4 = (const float4*)(&sxh[r][0]);
            float ax = 0.f, ay = 0.f, az = 0.f, aw = 0.f;
#pragma unroll 4
            for (int kk = 0; kk < KPAD / 4; ++kk) {
                float4 w = w4[kk];
                float4 v = xh4[kk];
                ax = fmaf(w.x, v.x, ax);
                ay = fmaf(w.y, v.y, ay);
                az = fmaf(w.z, v.z, az);
                aw = fmaf(w.w, v.w, aw);
            }
            sg[r][j] = bc[j] + ((ax + ay) + (az + aw));
        }
        __syncthreads();

        // ---- pointwise LSTM cell update (gate order i,f,g,o) ----
        {
            int m = 0;
            for (int k = jj; k < HD; k += 32, ++m) {
                float gi = sg[r][k];
                float gf = sg[r][150 + k];
                float gg = sg[r][300 + k];
                float go = sg[r][450 + k];
                float cn = sigf(gf) * creg[m] + sigf(gi) * tanh_fast(gg);
                creg[m] = cn;
                float h = sigf(go) * tanh_fast(cn);
                sxh[r][150 + k] = h;
            }
        }
        __syncthreads();

        // ---- coalesced copy of h to outputs (and outh at t==29) ----
        for (int i = tid; i < ROWS * 75; i += NTHREADS) {
            int rr = i / 75, kk = i % 75;
            float2 v = *(const float2*)&sxh[rr][150 + 2 * kk];
            *(float2*)(outputs + ((size_t)t * BATCH + row0 + rr) * HD + 2 * kk) = v;
            if (t == GATED - 1) {
                *(float2*)(outh + (size_t)(row0 + rr) * HD + 2 * kk) = v;
            }
        }

        if (t < GATED) {
            // ---- stop gate layer 1: [x|h] . w1c[j] -> relu -> st1 ----
            for (int j = jj; j < 50; j += 32) {
                const float4* w4  = (const float4*)(w1c + (size_t)j * KPAD);
                const float4* xh4 = (const float4*)(&sxh[r][0]);
                float ax = 0.f, ay = 0.f, az = 0.f, aw = 0.f;
#pragma unroll 4
                for (int kk = 0; kk < KPAD / 4; ++kk) {
                    float4 w = w4[kk];
                    float4 v = xh4[kk];
                    ax = fmaf(w.x, v.x, ax);
                    ay = fmaf(w.y, v.y, ay);
                    az = fmaf(w.z, v.z, az);
                    aw = fmaf(w.w, v.w, aw);
                }
                float s = b1[j] + ((ax + ay) + (az + aw));
                st1[r][j] = s > 0.0f ? s : 0.0f;
            }
            __syncthreads();

            // ---- layer 2: 25 outputs, dot-50 ----
            for (int j = jj; j < 25; j += 32) {
                float a = b2[j];
                for (int k2 = 0; k2 < 50; ++k2)
                    a = fmaf(w2[j * 50 + k2], st1[r][k2], a);
                st2[r][j] = a > 0.0f ? a : 0.0f;
            }
            __syncthreads();

            // ---- layer 3 + relu + softmax(2) ----
            if (tid < ROWS) {
                int rr = tid;
                float z0 = b3[0], z1 = b3[1];
                for (int k2 = 0; k2 < 25; ++k2) {
                    z0 = fmaf(w3[k2],      st2[rr][k2], z0);
                    z1 = fmaf(w3[25 + k2], st2[rr][k2], z1);
                }
                z0 = z0 > 0.0f ? z0 : 0.0f;
                z1 = z1 > 0.0f ? z1 : 0.0f;
                float mx = fmaxf(z0, z1);
                float e0 = __expf(z0 - mx), e1 = __expf(z1 - mx);
                float inv = 1.0f / (e0 + e1);
                size_t yb = ((size_t)t * BATCH + row0 + rr) * 2;
                ys[yb]     = e0 * inv;
                ys[yb + 1] = e1 * inv;
            }
            __syncthreads();
        } else {
            __syncthreads();  // protect sxh h-reads (copy-out) before next x overwrite phase ordering
        }
    }
}

extern "C" void kernel_launch(void* const* d_in, const int* in_sizes, int n_in,
                              void* d_out, int out_size, void* d_ws, size_t ws_size,
                              hipStream_t stream) {
    const float* x    = (const float*)d_in[0];
    const float* w_ih = (const float*)d_in[1];
    const float* w_hh = (const float*)d_in[2];
    const float* b_ih = (const float*)d_in[3];
    const float* b_hh = (const float*)d_in[4];
    const float* w1   = (const float*)d_in[5];
    const float* b1   = (const float*)d_in[6];
    const float* w2   = (const float*)d_in[7];
    const float* b2   = (const float*)d_in[8];
    const float* w3   = (const float*)d_in[9];
    const float* b3   = (const float*)d_in[10];

    float* out = (float*)d_out;
    float* ws  = (float*)d_ws;
    float* Wc  = ws;                          // 600*304
    float* w1c = ws + G4 * KPAD;              // 50*304
    float* bc  = ws + G4 * KPAD + 50 * KPAD;  // 600

    pack_weights<<<256, 256, 0, stream>>>(w_ih, w_hh, b_ih, b_hh, w1, Wc, w1c, bc);

    lstm_main<<<BATCH / ROWS, NTHREADS, 0, stream>>>(
        x, Wc, bc, w1c, b1, w2, b2, w3, b3,
        out, out + OFF_OUTPUTS, out + OFF_YS);
}